// Round 2
// baseline (403.982 us; speedup 1.0000x reference)
//
#include <hip/hip_runtime.h>
#include <stdint.h>
#include <stddef.h>

// SimplifiedLinearAttention on MI355X (gfx950) — FP32 in/out, f16 compute.
// Tolerance 2% relative; single-f16 MFMA (rel err ~2^-11) verified passing.
// R6 changes vs R5 (attn was latency-bound: 56KB LDS -> 2 blocks/CU, 3
// barriers, cross-wave pkv reduction for ~1.5 MFLOP/block):
//  * attn rewritten BARRIER-FREE. k/v MFMA fragments read directly from
//    global [c][t] layout (wave reads 16 rows x 64B = full sectors); kv
//    computed redundantly per wave (32 MFMAs, L2 serves waves 2-4); ksum
//    reduced in-register from the same ka fragments via shfl_xor over quads.
//    kvT/ksum/zbuf/fm are all wave-local (dwc mapping (cg=lr, xr=w*4+quad)
//    writes exactly the pixel rows its own wave's epilogue reads) -> only
//    lgkmcnt waits, zero __syncthreads.
//  * LDS 56448 -> 28160 B (fm 16K + 4x wave-private kvT 10K + ksum/zbuf).
// qkv/proj/cvt unchanged from R5.

typedef _Float16 f16;
typedef __attribute__((ext_vector_type(4))) _Float16 f16x4;
typedef __attribute__((ext_vector_type(8))) _Float16 f16x8;
typedef __attribute__((ext_vector_type(4))) float floatx4;

#define DEV __device__ __forceinline__

DEV void async16(const void* g, void* l) {
  __builtin_amdgcn_global_load_lds(
      (const __attribute__((address_space(1))) void*)g,
      (__attribute__((address_space(3))) void*)l,
      16, 0, 0);
}

DEV floatx4 mfma16(f16x8 a, f16x8 b, floatx4 c) {
  return __builtin_amdgcn_mfma_f32_16x16x32_f16(a, b, c, 0, 0, 0);
}

DEV f16x4 cvt4(float4 v) {
  f16x4 h;
  h[0] = (f16)v.x; h[1] = (f16)v.y; h[2] = (f16)v.z; h[3] = (f16)v.w;
  return h;
}

// ---------------------------------------------------------------------------
// K0: bulk fp32 -> f16 convert (grid-stride, float4 in / f16x4 out).
// ---------------------------------------------------------------------------
__global__ __launch_bounds__(256) void cvt_kernel(
    const float* __restrict__ src, f16* __restrict__ dst, int n4) {
  const int stride = gridDim.x * 256;
  for (int i = blockIdx.x * 256 + threadIdx.x; i < n4; i += stride) {
    float4 v = ((const float4*)src)[i];
    ((f16x4*)dst)[i] = cvt4(v);
  }
}

// ---------------------------------------------------------------------------
// K1: qkv GEMM, A/W pre-converted f16. grid 4608. bx = 72a + 8n + c ->
// m-tile 8a+c, n-tile n: same-m blocks share XCD for L2 reuse of the x tile.
// BK=64; tiles [128][64] f16 linear in LDS (global_load_lds), source-side
// XOR swizzle col16 ^= (row&7); frag reads apply the same XOR (2-way free).
// ---------------------------------------------------------------------------
__global__ __launch_bounds__(256) void qkv_kernel(
    const f16* __restrict__ A, const f16* __restrict__ W,
    const float* __restrict__ bias, const float* __restrict__ pos,
    f16* __restrict__ q_ws, f16* __restrict__ kT_ws, f16* __restrict__ vT_ws) {
  __shared__ __align__(16) f16 Af[128 * 64];
  __shared__ __align__(16) f16 Wf[128 * 64];
  const int tid = threadIdx.x;
  const int lane = tid & 63, wave = tid >> 6;
  const int quad = lane >> 4, lr = lane & 15;
  const int wm = wave >> 1, wn = wave & 1;
  const int bx = blockIdx.x;
  const int ga = bx / 72, rem = bx - ga * 72;
  const int nblk = rem >> 3, gc = rem & 7;
  const int m0 = (ga * 8 + gc) * 128, n0 = nblk * 128;
  const int rl = lane >> 3;           // row within 8-row chunk
  const int lcol = (lane & 7) ^ rl;   // logical col16 for this lane's LDS slot

  floatx4 acc[4][4] = {};

  // per-lane global base pointers for the 4 staged chunks (each wave: 4A+4W)
  const f16* ap[4];
  const f16* wp[4];
#pragma unroll
  for (int t2 = 0; t2 < 4; ++t2) {
    const int row = (wave * 4 + t2) * 8 + rl;
    ap[t2] = A + (size_t)(m0 + row) * 384 + lcol * 8;
    wp[t2] = W + (size_t)(n0 + row) * 384 + lcol * 8;
  }

  for (int kt = 0; kt < 6; ++kt) {
    __syncthreads();  // prior frag reads done
#pragma unroll
    for (int t2 = 0; t2 < 4; ++t2) {
      const int ch = wave * 4 + t2;
      async16(ap[t2] + kt * 64, (char*)Af + ch * 1024);
      async16(wp[t2] + kt * 64, (char*)Wf + ch * 1024);
    }
    __syncthreads();  // compiler drains vmcnt before s_barrier
#pragma unroll
    for (int s = 0; s < 2; ++s) {
      const int pc = ((quad + s * 4) ^ (lr & 7)) * 16;  // swizzled col byte
      f16x8 af[4], wf[4];
#pragma unroll
      for (int mt = 0; mt < 4; ++mt)
        af[mt] = *(const f16x8*)((const char*)Af +
                                 (wm * 64 + mt * 16 + lr) * 128 + pc);
#pragma unroll
      for (int nt = 0; nt < 4; ++nt)
        wf[nt] = *(const f16x8*)((const char*)Wf +
                                 (wn * 64 + nt * 16 + lr) * 128 + pc);
#pragma unroll
      for (int mt = 0; mt < 4; ++mt)
#pragma unroll
        for (int nt = 0; nt < 4; ++nt)
          acc[mt][nt] = mfma16(af[mt], wf[nt], acc[mt][nt]);
    }
  }

  float bv[4];
#pragma unroll
  for (int nt = 0; nt < 4; ++nt)
    bv[nt] = bias[n0 + wn * 64 + nt * 16 + lr];

  const int cls = nblk / 3;                 // 0=q 1=k 2=v
  const int cbase = (nblk - cls * 3) * 128; // channel base within class
  if (cls == 0) {
#pragma unroll
    for (int mt = 0; mt < 4; ++mt) {
#pragma unroll
      for (int r = 0; r < 4; ++r) {
        const int m = m0 + wm * 64 + mt * 16 + quad * 4 + r;
        const int bwin = m >> 8, t = m & 255;
#pragma unroll
        for (int nt = 0; nt < 4; ++nt) {
          const int c = cbase + wn * 64 + nt * 16 + lr;
          const int h = c >> 5, hd = c & 31;
          const float val = fmaxf(acc[mt][nt][r] + bv[nt], 0.f);
          q_ws[(size_t)(bwin * 12 + h) * 8192 + t * 32 + hd] = (f16)val;
        }
      }
    }
  } else {
#pragma unroll
    for (int mt = 0; mt < 4; ++mt) {
      const int mb = m0 + wm * 64 + mt * 16 + quad * 4;  // token base (4 consec)
      const int bwin = mb >> 8, t0 = mb & 255;
#pragma unroll
      for (int nt = 0; nt < 4; ++nt) {
        const int c = cbase + wn * 64 + nt * 16 + lr;
        const int h = c >> 5, hd = c & 31;
        f16x4 pk;
        if (cls == 1) {
#pragma unroll
          for (int r = 0; r < 4; ++r)
            pk[r] = (f16)fmaxf(acc[mt][nt][r] + bv[nt] + pos[(t0 + r) * 384 + c], 0.f);
          *(f16x4*)(kT_ws + (size_t)(bwin * 12 + h) * 8192 + hd * 256 + t0) = pk;
        } else {
#pragma unroll
          for (int r = 0; r < 4; ++r)
            pk[r] = (f16)(acc[mt][nt][r] + bv[nt]);
          *(f16x4*)(vT_ws + (size_t)(bwin * 12 + h) * 8192 + hd * 256 + t0) = pk;
        }
      }
    }
  }
}

// ---------------------------------------------------------------------------
// K2: attention + dwc. One block per (window,head), 256 threads, 4 waves.
// BARRIER-FREE: all cross-thread communication is wave-local (per-wave kvT /
// ksum / zbuf slices; dwc writes exactly its own wave's fm pixel rows).
// k/v/q MFMA fragments read directly from global (full-sector coalesced);
// kv computed redundantly per wave (L2 serves waves 2-4). LDS 28160 B.
// ---------------------------------------------------------------------------
__global__ __launch_bounds__(256) void attn_kernel(
    const f16* __restrict__ q_ws, const f16* __restrict__ kT_ws,
    const f16* __restrict__ vT_ws, const float* __restrict__ dwc_w,
    const float* __restrict__ dwc_b, f16* __restrict__ y_ws) {
  __shared__ __align__(16) f16 fmbuf[256 * 32];   // 16 KB, wave-local rows
  __shared__ __align__(16) f16 kvT[4][32 * 40];   // per-wave kv^T [d][c], pad 40
  __shared__ float ksum[4][32];                   // per-wave k column sums
  __shared__ float zbuf[256];                     // z_i, wave-local rows

  const int tid = threadIdx.x;
  const int lane = tid & 63, wave = tid >> 6;
  const int quad = lane >> 4, lr = lane & 15;
  const size_t base = (size_t)blockIdx.x * 8192;

  // ---- kv = k^T v over all 256 tokens (redundant per wave) + ksum ----
  {
    floatx4 kacc[2][2] = {};
    float ks0 = 0.f, ks1 = 0.f;
#pragma unroll
    for (int s = 0; s < 8; ++s) {
      f16x8 ka[2], vb[2];
#pragma unroll
      for (int m2 = 0; m2 < 2; ++m2) {
        const size_t off =
            base + (size_t)(m2 * 16 + lr) * 256 + s * 32 + quad * 8;
        ka[m2] = *(const f16x8*)(kT_ws + off);
        vb[m2] = *(const f16x8*)(vT_ws + off);
      }
#pragma unroll
      for (int j = 0; j < 8; ++j) {
        ks0 += (float)ka[0][j];
        ks1 += (float)ka[1][j];
      }
#pragma unroll
      for (int m2 = 0; m2 < 2; ++m2)
#pragma unroll
        for (int n2 = 0; n2 < 2; ++n2)
          kacc[m2][n2] = mfma16(ka[m2], vb[n2], kacc[m2][n2]);
    }
    // ksum: reduce over the 4 quads (lane bits 4,5); lane holds channel lr / 16+lr
    ks0 += __shfl_xor(ks0, 16); ks0 += __shfl_xor(ks0, 32);
    ks1 += __shfl_xor(ks1, 16); ks1 += __shfl_xor(ks1, 32);
    if (quad == 0) {
      ksum[wave][lr] = ks0;
      ksum[wave][16 + lr] = ks1;
    }
    // kv -> kvT[wave][d][c] f16 (C layout: row=c=m2*16+quad*4+r, col=d=n2*16+lr)
#pragma unroll
    for (int m2 = 0; m2 < 2; ++m2)
#pragma unroll
      for (int n2 = 0; n2 < 2; ++n2)
#pragma unroll
        for (int r = 0; r < 4; ++r)
          kvT[wave][(n2 * 16 + lr) * 40 + m2 * 16 + quad * 4 + r] =
              (f16)kacc[m2][n2][r];
  }

  // ---- z_i = 1/(q_i . ksum + eps) for row i = wave*64 + lane ----
  {
    const f16* qrow = q_ws + base + (size_t)(wave * 64 + lane) * 32;
    float dot = 0.f;
#pragma unroll
    for (int c8 = 0; c8 < 32; c8 += 8) {
      f16x8 qq = *(const f16x8*)(qrow + c8);
#pragma unroll
      for (int j = 0; j < 8; ++j) dot += (float)qq[j] * ksum[wave][c8 + j];
    }
    zbuf[wave * 64 + lane] = 1.f / (dot + 1e-6f);
  }

  // ---- dwc (fp32): thread owns channels {2cg,2cg+1}, spatial w-row xr ----
  // xr = wave*4 + quad -> writes fm pixels [wave*64, wave*64+64): wave-local.
  {
    uint32_t* fmu = (uint32_t*)fmbuf;  // fm [256 pix][16 pairs] packed 2xf16
    const int cg = lr, xr = wave * 4 + quad, c0 = cg * 2;
    float a0[16], a1[16];
    const float b0v = dwc_b[c0], b1v = dwc_b[c0 + 1];
#pragma unroll
    for (int yy = 0; yy < 16; ++yy) { a0[yy] = b0v; a1[yy] = b1v; }
    const f16* v0 = vT_ws + base + c0 * 256;  // channel c0; +256 -> c0+1
#pragma unroll
    for (int dx = 0; dx < 5; ++dx) {
      const int xx = xr + dx - 2;
      if (xx < 0 || xx > 15) continue;
      float r0[16], r1[16];
      f16x8 h0 = *(const f16x8*)(v0 + xx * 16);
      f16x8 h1 = *(const f16x8*)(v0 + xx * 16 + 8);
      f16x8 h2 = *(const f16x8*)(v0 + 256 + xx * 16);
      f16x8 h3 = *(const f16x8*)(v0 + 256 + xx * 16 + 8);
#pragma unroll
      for (int j = 0; j < 8; ++j) {
        r0[j] = (float)h0[j]; r0[8 + j] = (float)h1[j];
        r1[j] = (float)h2[j]; r1[8 + j] = (float)h3[j];
      }
#pragma unroll
      for (int dy = 0; dy < 5; ++dy) {
        const float w0 = dwc_w[c0 * 25 + dx * 5 + dy];
        const float w1 = dwc_w[(c0 + 1) * 25 + dx * 5 + dy];
#pragma unroll
        for (int yy = 0; yy < 16; ++yy) {
          const int ys = yy + dy - 2;
          if (ys >= 0 && ys < 16) {
            a0[yy] += w0 * r0[ys];
            a1[yy] += w1 * r1[ys];
          }
        }
      }
    }
#pragma unroll
    for (int yy = 0; yy < 16; ++yy) {
      const uint32_t lo = (uint32_t)__builtin_bit_cast(uint16_t, (f16)a0[yy]);
      const uint32_t hi = (uint32_t)__builtin_bit_cast(uint16_t, (f16)a1[yy]);
      fmu[(xr * 16 + yy) * 16 + cg] = lo | (hi << 16);
    }
  }

  // ---- out = z*(q@kv) + fm -> y (aliases q; wave-local rows) ----
  {
    floatx4 oacc[4][2] = {};
    f16x8 qa[4], kb[2];
#pragma unroll
    for (int mm = 0; mm < 4; ++mm)
      qa[mm] = *(const f16x8*)(q_ws + base +
                               (size_t)(wave * 64 + mm * 16 + lr) * 32 + quad * 8);
#pragma unroll
    for (int nt = 0; nt < 2; ++nt)
      kb[nt] = *(const f16x8*)(kvT[wave] + (nt * 16 + lr) * 40 + quad * 8);
#pragma unroll
    for (int mm = 0; mm < 4; ++mm)
#pragma unroll
      for (int nt = 0; nt < 2; ++nt)
        oacc[mm][nt] = mfma16(qa[mm], kb[nt], oacc[mm][nt]);

#pragma unroll
    for (int mm = 0; mm < 4; ++mm) {
#pragma unroll
      for (int r = 0; r < 4; ++r) {
        const int i = wave * 64 + mm * 16 + quad * 4 + r;
        const float zi = zbuf[i];
#pragma unroll
        for (int nt = 0; nt < 2; ++nt) {
          const int d = nt * 16 + lr;
          const float val = oacc[mm][nt][r] * zi + (float)fmbuf[i * 32 + d];
          y_ws[base + (size_t)i * 32 + d] = (f16)val;
        }
      }
    }
  }
}

// ---------------------------------------------------------------------------
// K3: out = y @ proj_w^T + proj_b (fp32 out). grid 1536, bx = 24a + 8n + c.
// BK=64: each K-tile covers TWO heads of y via per-lane source addresses
// (y layout [head][token][32] f16). Both tiles global_load_lds-staged with
// the same XOR source swizzle as K1; W pre-converted f16 (pwh, kT region).
// ---------------------------------------------------------------------------
__global__ __launch_bounds__(256) void proj_kernel(
    const f16* __restrict__ Y, const f16* __restrict__ Wh,
    const float* __restrict__ bias, float* __restrict__ out) {
  __shared__ __align__(16) f16 Af[128 * 64];
  __shared__ __align__(16) f16 Wf[128 * 64];
  const int tid = threadIdx.x;
  const int lane = tid & 63, wave = tid >> 6;
  const int quad = lane >> 4, lr = lane & 15;
  const int wm = wave >> 1, wn = wave & 1;
  const int bx = blockIdx.x;
  const int ga = bx / 24, rem = bx - ga * 24;
  const int nblk = rem >> 3, gc = rem & 7;
  const int m0 = (ga * 8 + gc) * 128, n0 = nblk * 128;
  const int bwin = m0 >> 8, tbase = m0 & 255;
  const int rl = lane >> 3;
  const int lcol = (lane & 7) ^ rl;   // logical col16: 0..3 head 2kt, 4..7 head 2kt+1

  floatx4 acc[4][4] = {};

  const f16* ap[4];  // head-pair stride per kt: 2*8192 f16
  const f16* wp[4];
#pragma unroll
  for (int t2 = 0; t2 < 4; ++t2) {
    const int rowl = (wave * 4 + t2) * 8 + rl;
    ap[t2] = Y + (size_t)(bwin * 12 + (lcol >> 2)) * 8192 +
             (size_t)(tbase + rowl) * 32 + (lcol & 3) * 8;
    wp[t2] = Wh + (size_t)(n0 + rowl) * 384 + lcol * 8;
  }

  for (int kt = 0; kt < 6; ++kt) {
    __syncthreads();
#pragma unroll
    for (int t2 = 0; t2 < 4; ++t2) {
      const int ch = wave * 4 + t2;
      async16(ap[t2] + (size_t)kt * 16384, (char*)Af + ch * 1024);
      async16(wp[t2] + kt * 64, (char*)Wf + ch * 1024);
    }
    __syncthreads();
#pragma unroll
    for (int s = 0; s < 2; ++s) {
      const int pc = ((quad + s * 4) ^ (lr & 7)) * 16;
      f16x8 af[4], wf[4];
#pragma unroll
      for (int mt = 0; mt < 4; ++mt)
        af[mt] = *(const f16x8*)((const char*)Af +
                                 (wm * 64 + mt * 16 + lr) * 128 + pc);
#pragma unroll
      for (int nt = 0; nt < 4; ++nt)
        wf[nt] = *(const f16x8*)((const char*)Wf +
                                 (wn * 64 + nt * 16 + lr) * 128 + pc);
#pragma unroll
      for (int mt = 0; mt < 4; ++mt)
#pragma unroll
        for (int nt = 0; nt < 4; ++nt)
          acc[mt][nt] = mfma16(af[mt], wf[nt], acc[mt][nt]);
    }
  }

  float bv[4];
#pragma unroll
  for (int nt = 0; nt < 4; ++nt)
    bv[nt] = bias[n0 + wn * 64 + nt * 16 + lr];
#pragma unroll
  for (int mt = 0; mt < 4; ++mt)
#pragma unroll
    for (int r = 0; r < 4; ++r) {
      const int m = m0 + wm * 64 + mt * 16 + quad * 4 + r;
#pragma unroll
      for (int nt = 0; nt < 4; ++nt) {
        const int n = n0 + wn * 64 + nt * 16 + lr;
        out[(size_t)m * 384 + n] = acc[mt][nt][r] + bv[nt];
      }
    }
}

// ---------------------------------------------------------------------------
extern "C" void kernel_launch(void* const* d_in, const int* in_sizes, int n_in,
                              void* d_out, int out_size, void* d_ws, size_t ws_size,
                              hipStream_t stream) {
  const float* x = (const float*)d_in[0];
  const float* qkv_w = (const float*)d_in[1];
  const float* qkv_b = (const float*)d_in[2];
  const float* pos = (const float*)d_in[3];
  const float* dwc_w = (const float*)d_in[4];
  const float* dwc_b = (const float*)d_in[5];
  const float* proj_w = (const float*)d_in[6];
  const float* proj_b = (const float*)d_in[7];
  float* out = (float*)d_out;

  // ws: q/y @0, kT @50331648, vT @100663296; total 150994944 B (144 MiB)
  const size_t WS_NEEDED = 150994944;
  if (ws_size < WS_NEEDED) return;  // diagnostic: absmax stays 1.1328125

  char* ws = (char*)d_ws;
  f16* q_ws = (f16*)(ws);                  // [3072][256][32], later y
  f16* kT_ws = (f16*)(ws + 50331648);      // [3072][32][256]
  f16* vT_ws = (f16*)(ws + 100663296);     // [3072][32][256]

  // f16 staging areas inside d_out (100.6 MB): xh [65536][384] = 50.3 MB,
  // qwh [1152][384] = 0.88 MB. Both dead before proj overwrites d_out.
  f16* xh = (f16*)d_out;
  f16* qwh = (f16*)((char*)d_out + 50331648);
  // proj_w f16 lives in the kT region (dead after attn_kernel).
  f16* pwh = (f16*)(ws + 50331648);

  cvt_kernel<<<2048, 256, 0, stream>>>(x, xh, 6291456);        // 96 MB read
  cvt_kernel<<<432, 256, 0, stream>>>(qkv_w, qwh, 110592);
  qkv_kernel<<<4608, 256, 0, stream>>>(xh, qwh, qkv_b, pos,
                                       q_ws, kT_ws, vT_ws);
  attn_kernel<<<3072, 256, 0, stream>>>(q_ws, kT_ws, vT_ws,
                                        dwc_w, dwc_b, q_ws /* y aliases q */);
  cvt_kernel<<<144, 256, 0, stream>>>(proj_w, pwh, 36864);
  proj_kernel<<<1536, 256, 0, stream>>>(q_ws, pwh, proj_b, out);
}

// Round 3
// 350.971 us; speedup vs baseline: 1.1510x; 1.1510x over previous
//
#include <hip/hip_runtime.h>
#include <stdint.h>
#include <stddef.h>

// SimplifiedLinearAttention on MI355X (gfx950) — FP32 in/out, f16 compute.
// Tolerance 2% relative; single-f16 MFMA (rel err ~2^-11) verified passing.
// R7 changes vs R6 (R6's barrier-free attn REGRESSED ~30us: dropping LDS
// staging traded 32KB staged reads for ~130KB/block of 200-900cy direct
// global reads + a 2nd 50MB q pass. Barriers weren't the cost):
//  * attn reverted to R5's staged-LDS structure, BUT kv output is
//    partitioned across waves (wave w owns 16x16 fragment (w&1, w>>1) over
//    full K=256) instead of partitioning K: pkv (18.4KB) + cross-wave
//    reduce + barrier B3 deleted. ksum finalized per-wave (redundant,
//    ksum[4][32]); z computed from the epilogue's own qa fragments via
//    quad shfl-reduce (q read from HBM once, not twice).
//  * LDS 56448 -> 38400 B: 2 -> 4 blocks/CU (16 waves/CU), 2 barriers.
// qkv/proj/cvt unchanged.

typedef _Float16 f16;
typedef __attribute__((ext_vector_type(4))) _Float16 f16x4;
typedef __attribute__((ext_vector_type(8))) _Float16 f16x8;
typedef __attribute__((ext_vector_type(4))) float floatx4;

#define DEV __device__ __forceinline__

DEV void async16(const void* g, void* l) {
  __builtin_amdgcn_global_load_lds(
      (const __attribute__((address_space(1))) void*)g,
      (__attribute__((address_space(3))) void*)l,
      16, 0, 0);
}

DEV floatx4 mfma16(f16x8 a, f16x8 b, floatx4 c) {
  return __builtin_amdgcn_mfma_f32_16x16x32_f16(a, b, c, 0, 0, 0);
}

DEV f16x4 cvt4(float4 v) {
  f16x4 h;
  h[0] = (f16)v.x; h[1] = (f16)v.y; h[2] = (f16)v.z; h[3] = (f16)v.w;
  return h;
}

// ---------------------------------------------------------------------------
// K0: bulk fp32 -> f16 convert (grid-stride, float4 in / f16x4 out).
// ---------------------------------------------------------------------------
__global__ __launch_bounds__(256) void cvt_kernel(
    const float* __restrict__ src, f16* __restrict__ dst, int n4) {
  const int stride = gridDim.x * 256;
  for (int i = blockIdx.x * 256 + threadIdx.x; i < n4; i += stride) {
    float4 v = ((const float4*)src)[i];
    ((f16x4*)dst)[i] = cvt4(v);
  }
}

// ---------------------------------------------------------------------------
// K1: qkv GEMM, A/W pre-converted f16. grid 4608. bx = 72a + 8n + c ->
// m-tile 8a+c, n-tile n: same-m blocks share XCD for L2 reuse of the x tile.
// BK=64; tiles [128][64] f16 linear in LDS (global_load_lds), source-side
// XOR swizzle col16 ^= (row&7); frag reads apply the same XOR (2-way free).
// ---------------------------------------------------------------------------
__global__ __launch_bounds__(256) void qkv_kernel(
    const f16* __restrict__ A, const f16* __restrict__ W,
    const float* __restrict__ bias, const float* __restrict__ pos,
    f16* __restrict__ q_ws, f16* __restrict__ kT_ws, f16* __restrict__ vT_ws) {
  __shared__ __align__(16) f16 Af[128 * 64];
  __shared__ __align__(16) f16 Wf[128 * 64];
  const int tid = threadIdx.x;
  const int lane = tid & 63, wave = tid >> 6;
  const int quad = lane >> 4, lr = lane & 15;
  const int wm = wave >> 1, wn = wave & 1;
  const int bx = blockIdx.x;
  const int ga = bx / 72, rem = bx - ga * 72;
  const int nblk = rem >> 3, gc = rem & 7;
  const int m0 = (ga * 8 + gc) * 128, n0 = nblk * 128;
  const int rl = lane >> 3;           // row within 8-row chunk
  const int lcol = (lane & 7) ^ rl;   // logical col16 for this lane's LDS slot

  floatx4 acc[4][4] = {};

  // per-lane global base pointers for the 4 staged chunks (each wave: 4A+4W)
  const f16* ap[4];
  const f16* wp[4];
#pragma unroll
  for (int t2 = 0; t2 < 4; ++t2) {
    const int row = (wave * 4 + t2) * 8 + rl;
    ap[t2] = A + (size_t)(m0 + row) * 384 + lcol * 8;
    wp[t2] = W + (size_t)(n0 + row) * 384 + lcol * 8;
  }

  for (int kt = 0; kt < 6; ++kt) {
    __syncthreads();  // prior frag reads done
#pragma unroll
    for (int t2 = 0; t2 < 4; ++t2) {
      const int ch = wave * 4 + t2;
      async16(ap[t2] + kt * 64, (char*)Af + ch * 1024);
      async16(wp[t2] + kt * 64, (char*)Wf + ch * 1024);
    }
    __syncthreads();  // compiler drains vmcnt before s_barrier
#pragma unroll
    for (int s = 0; s < 2; ++s) {
      const int pc = ((quad + s * 4) ^ (lr & 7)) * 16;  // swizzled col byte
      f16x8 af[4], wf[4];
#pragma unroll
      for (int mt = 0; mt < 4; ++mt)
        af[mt] = *(const f16x8*)((const char*)Af +
                                 (wm * 64 + mt * 16 + lr) * 128 + pc);
#pragma unroll
      for (int nt = 0; nt < 4; ++nt)
        wf[nt] = *(const f16x8*)((const char*)Wf +
                                 (wn * 64 + nt * 16 + lr) * 128 + pc);
#pragma unroll
      for (int mt = 0; mt < 4; ++mt)
#pragma unroll
        for (int nt = 0; nt < 4; ++nt)
          acc[mt][nt] = mfma16(af[mt], wf[nt], acc[mt][nt]);
    }
  }

  float bv[4];
#pragma unroll
  for (int nt = 0; nt < 4; ++nt)
    bv[nt] = bias[n0 + wn * 64 + nt * 16 + lr];

  const int cls = nblk / 3;                 // 0=q 1=k 2=v
  const int cbase = (nblk - cls * 3) * 128; // channel base within class
  if (cls == 0) {
#pragma unroll
    for (int mt = 0; mt < 4; ++mt) {
#pragma unroll
      for (int r = 0; r < 4; ++r) {
        const int m = m0 + wm * 64 + mt * 16 + quad * 4 + r;
        const int bwin = m >> 8, t = m & 255;
#pragma unroll
        for (int nt = 0; nt < 4; ++nt) {
          const int c = cbase + wn * 64 + nt * 16 + lr;
          const int h = c >> 5, hd = c & 31;
          const float val = fmaxf(acc[mt][nt][r] + bv[nt], 0.f);
          q_ws[(size_t)(bwin * 12 + h) * 8192 + t * 32 + hd] = (f16)val;
        }
      }
    }
  } else {
#pragma unroll
    for (int mt = 0; mt < 4; ++mt) {
      const int mb = m0 + wm * 64 + mt * 16 + quad * 4;  // token base (4 consec)
      const int bwin = mb >> 8, t0 = mb & 255;
#pragma unroll
      for (int nt = 0; nt < 4; ++nt) {
        const int c = cbase + wn * 64 + nt * 16 + lr;
        const int h = c >> 5, hd = c & 31;
        f16x4 pk;
        if (cls == 1) {
#pragma unroll
          for (int r = 0; r < 4; ++r)
            pk[r] = (f16)fmaxf(acc[mt][nt][r] + bv[nt] + pos[(t0 + r) * 384 + c], 0.f);
          *(f16x4*)(kT_ws + (size_t)(bwin * 12 + h) * 8192 + hd * 256 + t0) = pk;
        } else {
#pragma unroll
          for (int r = 0; r < 4; ++r)
            pk[r] = (f16)(acc[mt][nt][r] + bv[nt]);
          *(f16x4*)(vT_ws + (size_t)(bwin * 12 + h) * 8192 + hd * 256 + t0) = pk;
        }
      }
    }
  }
}

// ---------------------------------------------------------------------------
// K2: attention + dwc. One block per (window,head), 256 threads, 4 waves.
// Staged-LDS (R5 structure) but kv partitioned by OUTPUT fragment across
// waves (wave w: m2=w&1, n2=w>>1, full K=256) -> no pkv, no cross-wave
// reduce, 2 barriers. ksum finalized per-wave; z from epilogue qa frags.
// LDS 38400 B -> 4 blocks/CU.
// ---------------------------------------------------------------------------
__global__ __launch_bounds__(256) void attn_kernel(
    const f16* __restrict__ q_ws, const f16* __restrict__ kT_ws,
    const f16* __restrict__ vT_ws, const float* __restrict__ dwc_w,
    const float* __restrict__ dwc_b, f16* __restrict__ y_ws) {
  __shared__ __align__(16) char khb[16640];   // kT chunks; later fm [256][32] f16
  __shared__ __align__(16) char vhb[16640];   // vT chunks
  __shared__ float psum[8 * 32];              // ksum partials
  __shared__ float ksum[4][32];               // per-wave final k column sums
  __shared__ float zbuf[256];                 // z_i (wave-local rows)
  __shared__ __align__(16) f16 kvT[32 * 40];  // kv^T [d][c], pad 40

  const int tid = threadIdx.x;
  const int lane = tid & 63, wave = tid >> 6;
  const int quad = lane >> 4, lr = lane & 15;
  const size_t base = (size_t)blockIdx.x * 8192;

  // ---- stage kT, vT (channel c at (c>>1)*1040 + (c&1)*512 bytes) ----
#pragma unroll
  for (int t2 = 0; t2 < 4; ++t2) {
    const int is = wave * 4 + t2;
    async16(kT_ws + base + is * 512 + lane * 8, khb + is * 1040);
    async16(vT_ws + base + is * 512 + lane * 8, vhb + is * 1040);
  }
  __syncthreads();  // B1

  // ---- ksum partials: thread (c=tid&31, seg=tid>>5) sums 32 tokens ----
  {
    const int c = tid & 31, seg = tid >> 5;
    const char* kr = khb + (c >> 1) * 1040 + (c & 1) * 512;
    float s = 0.f;
#pragma unroll
    for (int j8 = 0; j8 < 32; j8 += 8) {
      f16x8 a = *(const f16x8*)(kr + (seg * 32 + j8) * 2);
#pragma unroll
      for (int j = 0; j < 8; ++j) s += (float)a[j];
    }
    psum[seg * 32 + c] = s;
  }
  // ---- kv fragment (m2=wave&1, n2=wave>>1) over full K=256 ----
  {
    const int m2 = wave & 1, n2 = wave >> 1;
    const int ck = m2 * 16 + lr, cv = n2 * 16 + lr;
    const char* krow = khb + (ck >> 1) * 1040 + (ck & 1) * 512;
    const char* vrow = vhb + (cv >> 1) * 1040 + (cv & 1) * 512;
    floatx4 kacc = {};
#pragma unroll
    for (int s = 0; s < 8; ++s) {
      f16x8 ka = *(const f16x8*)(krow + (s * 32 + quad * 8) * 2);
      f16x8 vb = *(const f16x8*)(vrow + (s * 32 + quad * 8) * 2);
      kacc = mfma16(ka, vb, kacc);
    }
    // C layout: row c = m2*16 + quad*4 + r, col d = n2*16 + lr.
    // kvT[d][c]: 4 consecutive c -> one f16x4 store (8B aligned).
    f16x4 kk;
#pragma unroll
    for (int r = 0; r < 4; ++r) kk[r] = (f16)kacc[r];
    *(f16x4*)(kvT + (n2 * 16 + lr) * 40 + m2 * 16 + quad * 4) = kk;
  }
  __syncthreads();  // B2 — khb/vhb reads + psum + kvT writes done

  // ---- ksum final (each wave, redundant; lanes 0..31) ----
  if (lane < 32) {
    float s = 0.f;
#pragma unroll
    for (int seg = 0; seg < 8; ++seg) s += psum[seg * 32 + lane];
    ksum[wave][lane] = s;
  }

  // ---- dwc (fp32): thread owns channels {2cg,2cg+1}, w-row xr = wave*4+quad
  // -> writes fm pixels [wave*64, wave*64+64): wave-local. fm overwrites khb.
  {
    uint32_t* fmu = (uint32_t*)khb;  // fm [256 pix][16 pairs] packed 2xf16
    const int cg = lr, xr = wave * 4 + quad, c0 = cg * 2;
    float a0[16], a1[16];
    const float b0v = dwc_b[c0], b1v = dwc_b[c0 + 1];
#pragma unroll
    for (int yy = 0; yy < 16; ++yy) { a0[yy] = b0v; a1[yy] = b1v; }
    const char* v0 = vhb + cg * 1040;  // channel c0 (even); +512 -> c0+1
#pragma unroll
    for (int dx = 0; dx < 5; ++dx) {
      const int xx = xr + dx - 2;
      if (xx < 0 || xx > 15) continue;
      float r0[16], r1[16];
      f16x8 h0 = *(const f16x8*)(v0 + xx * 32);
      f16x8 h1 = *(const f16x8*)(v0 + xx * 32 + 16);
      f16x8 h2 = *(const f16x8*)(v0 + 512 + xx * 32);
      f16x8 h3 = *(const f16x8*)(v0 + 512 + xx * 32 + 16);
#pragma unroll
      for (int j = 0; j < 8; ++j) {
        r0[j] = (float)h0[j]; r0[8 + j] = (float)h1[j];
        r1[j] = (float)h2[j]; r1[8 + j] = (float)h3[j];
      }
#pragma unroll
      for (int dy = 0; dy < 5; ++dy) {
        const float w0 = dwc_w[c0 * 25 + dx * 5 + dy];
        const float w1 = dwc_w[(c0 + 1) * 25 + dx * 5 + dy];
#pragma unroll
        for (int yy = 0; yy < 16; ++yy) {
          const int ys = yy + dy - 2;
          if (ys >= 0 && ys < 16) {
            a0[yy] += w0 * r0[ys];
            a1[yy] += w1 * r1[ys];
          }
        }
      }
    }
#pragma unroll
    for (int yy = 0; yy < 16; ++yy) {
      const uint32_t lo = (uint32_t)__builtin_bit_cast(uint16_t, (f16)a0[yy]);
      const uint32_t hi = (uint32_t)__builtin_bit_cast(uint16_t, (f16)a1[yy]);
      fmu[(xr * 16 + yy) * 16 + cg] = lo | (hi << 16);
    }
  }

  // ---- out = z*(q@kv) + fm -> y (aliases q; wave-local rows) ----
  {
    f16x8 qa[4], kb[2];
#pragma unroll
    for (int mm = 0; mm < 4; ++mm)
      qa[mm] = *(const f16x8*)(q_ws + base +
                               (size_t)(wave * 64 + mm * 16 + lr) * 32 + quad * 8);

    // z from qa frags: channels quad*8..+7; reduce over quads via shfl_xor.
    float ksv[8];
#pragma unroll
    for (int j = 0; j < 8; ++j) ksv[j] = ksum[wave][quad * 8 + j];
#pragma unroll
    for (int mm = 0; mm < 4; ++mm) {
      float dot = 0.f;
#pragma unroll
      for (int j = 0; j < 8; ++j) dot += (float)qa[mm][j] * ksv[j];
      dot += __shfl_xor(dot, 16);
      dot += __shfl_xor(dot, 32);
      if (quad == 0) zbuf[wave * 64 + mm * 16 + lr] = 1.f / (dot + 1e-6f);
    }

    floatx4 oacc[4][2] = {};
#pragma unroll
    for (int nt = 0; nt < 2; ++nt)
      kb[nt] = *(const f16x8*)(kvT + (nt * 16 + lr) * 40 + quad * 8);
#pragma unroll
    for (int mm = 0; mm < 4; ++mm)
#pragma unroll
      for (int nt = 0; nt < 2; ++nt)
        oacc[mm][nt] = mfma16(qa[mm], kb[nt], oacc[mm][nt]);

    const f16* fmb = (const f16*)khb;
#pragma unroll
    for (int mm = 0; mm < 4; ++mm) {
#pragma unroll
      for (int r = 0; r < 4; ++r) {
        const int i = wave * 64 + mm * 16 + quad * 4 + r;
        const float zi = zbuf[i];
#pragma unroll
        for (int nt = 0; nt < 2; ++nt) {
          const int d = nt * 16 + lr;
          const float val = oacc[mm][nt][r] * zi + (float)fmb[i * 32 + d];
          y_ws[base + (size_t)i * 32 + d] = (f16)val;
        }
      }
    }
  }
}

// ---------------------------------------------------------------------------
// K3: out = y @ proj_w^T + proj_b (fp32 out). grid 1536, bx = 24a + 8n + c.
// BK=64: each K-tile covers TWO heads of y via per-lane source addresses
// (y layout [head][token][32] f16). Both tiles global_load_lds-staged with
// the same XOR source swizzle as K1; W pre-converted f16 (pwh, kT region).
// ---------------------------------------------------------------------------
__global__ __launch_bounds__(256) void proj_kernel(
    const f16* __restrict__ Y, const f16* __restrict__ Wh,
    const float* __restrict__ bias, float* __restrict__ out) {
  __shared__ __align__(16) f16 Af[128 * 64];
  __shared__ __align__(16) f16 Wf[128 * 64];
  const int tid = threadIdx.x;
  const int lane = tid & 63, wave = tid >> 6;
  const int quad = lane >> 4, lr = lane & 15;
  const int wm = wave >> 1, wn = wave & 1;
  const int bx = blockIdx.x;
  const int ga = bx / 24, rem = bx - ga * 24;
  const int nblk = rem >> 3, gc = rem & 7;
  const int m0 = (ga * 8 + gc) * 128, n0 = nblk * 128;
  const int bwin = m0 >> 8, tbase = m0 & 255;
  const int rl = lane >> 3;
  const int lcol = (lane & 7) ^ rl;   // logical col16: 0..3 head 2kt, 4..7 head 2kt+1

  floatx4 acc[4][4] = {};

  const f16* ap[4];  // head-pair stride per kt: 2*8192 f16
  const f16* wp[4];
#pragma unroll
  for (int t2 = 0; t2 < 4; ++t2) {
    const int rowl = (wave * 4 + t2) * 8 + rl;
    ap[t2] = Y + (size_t)(bwin * 12 + (lcol >> 2)) * 8192 +
             (size_t)(tbase + rowl) * 32 + (lcol & 3) * 8;
    wp[t2] = Wh + (size_t)(n0 + rowl) * 384 + lcol * 8;
  }

  for (int kt = 0; kt < 6; ++kt) {
    __syncthreads();
#pragma unroll
    for (int t2 = 0; t2 < 4; ++t2) {
      const int ch = wave * 4 + t2;
      async16(ap[t2] + (size_t)kt * 16384, (char*)Af + ch * 1024);
      async16(wp[t2] + kt * 64, (char*)Wf + ch * 1024);
    }
    __syncthreads();
#pragma unroll
    for (int s = 0; s < 2; ++s) {
      const int pc = ((quad + s * 4) ^ (lr & 7)) * 16;
      f16x8 af[4], wf[4];
#pragma unroll
      for (int mt = 0; mt < 4; ++mt)
        af[mt] = *(const f16x8*)((const char*)Af +
                                 (wm * 64 + mt * 16 + lr) * 128 + pc);
#pragma unroll
      for (int nt = 0; nt < 4; ++nt)
        wf[nt] = *(const f16x8*)((const char*)Wf +
                                 (wn * 64 + nt * 16 + lr) * 128 + pc);
#pragma unroll
      for (int mt = 0; mt < 4; ++mt)
#pragma unroll
        for (int nt = 0; nt < 4; ++nt)
          acc[mt][nt] = mfma16(af[mt], wf[nt], acc[mt][nt]);
    }
  }

  float bv[4];
#pragma unroll
  for (int nt = 0; nt < 4; ++nt)
    bv[nt] = bias[n0 + wn * 64 + nt * 16 + lr];
#pragma unroll
  for (int mt = 0; mt < 4; ++mt)
#pragma unroll
    for (int r = 0; r < 4; ++r) {
      const int m = m0 + wm * 64 + mt * 16 + quad * 4 + r;
#pragma unroll
      for (int nt = 0; nt < 4; ++nt) {
        const int n = n0 + wn * 64 + nt * 16 + lr;
        out[(size_t)m * 384 + n] = acc[mt][nt][r] + bv[nt];
      }
    }
}

// ---------------------------------------------------------------------------
extern "C" void kernel_launch(void* const* d_in, const int* in_sizes, int n_in,
                              void* d_out, int out_size, void* d_ws, size_t ws_size,
                              hipStream_t stream) {
  const float* x = (const float*)d_in[0];
  const float* qkv_w = (const float*)d_in[1];
  const float* qkv_b = (const float*)d_in[2];
  const float* pos = (const float*)d_in[3];
  const float* dwc_w = (const float*)d_in[4];
  const float* dwc_b = (const float*)d_in[5];
  const float* proj_w = (const float*)d_in[6];
  const float* proj_b = (const float*)d_in[7];
  float* out = (float*)d_out;

  // ws: q/y @0, kT @50331648, vT @100663296; total 150994944 B (144 MiB)
  const size_t WS_NEEDED = 150994944;
  if (ws_size < WS_NEEDED) return;  // diagnostic: absmax stays 1.1328125

  char* ws = (char*)d_ws;
  f16* q_ws = (f16*)(ws);                  // [3072][256][32], later y
  f16* kT_ws = (f16*)(ws + 50331648);      // [3072][32][256]
  f16* vT_ws = (f16*)(ws + 100663296);     // [3072][32][256]

  // f16 staging areas inside d_out (100.6 MB): xh [65536][384] = 50.3 MB,
  // qwh [1152][384] = 0.88 MB. Both dead before proj overwrites d_out.
  f16* xh = (f16*)d_out;
  f16* qwh = (f16*)((char*)d_out + 50331648);
  // proj_w f16 lives in the kT region (dead after attn_kernel).
  f16* pwh = (f16*)(ws + 50331648);

  cvt_kernel<<<2048, 256, 0, stream>>>(x, xh, 6291456);        // 96 MB read
  cvt_kernel<<<432, 256, 0, stream>>>(qkv_w, qwh, 110592);
  qkv_kernel<<<4608, 256, 0, stream>>>(xh, qwh, qkv_b, pos,
                                       q_ws, kT_ws, vT_ws);
  attn_kernel<<<3072, 256, 0, stream>>>(q_ws, kT_ws, vT_ws,
                                        dwc_w, dwc_b, q_ws /* y aliases q */);
  cvt_kernel<<<144, 256, 0, stream>>>(proj_w, pwh, 36864);
  proj_kernel<<<1536, 256, 0, stream>>>(q_ws, pwh, proj_b, out);
}